// Round 7
// baseline (1218.010 us; speedup 1.0000x reference)
//
#include <hip/hip_runtime.h>
#include <hip/hip_bf16.h>

#define NN 20000
#define NP 20032            // padded to 32*626
#define NE 320000
#define RR 8
#define DD 256
#define LL 6
#define EED 32
#define BB 64
#define KK 32
#define MM (NN * RR)        // 160000 segments, key = dst*8 + rel
#define NSB 79              // scan blocks: ceil(160000 / 2048)
#define NB2 626             // row blocks of 32
#define HSTR 260            // padded h-tile row stride (floats)
#define ES_CAP 1280         // per-block staged edge-list capacity (avg 512, max ~650)

typedef __bf16 bf8 __attribute__((ext_vector_type(8)));
typedef float f4 __attribute__((ext_vector_type(4)));

__device__ inline float lo2f(unsigned v) { return __uint_as_float(v << 16); }
__device__ inline float hi2f(unsigned v) { return __uint_as_float(v & 0xffff0000u); }
__device__ inline unsigned short f2bf(float f) {
    unsigned u = __float_as_uint(f);
    return (unsigned short)((u + 0x7fff + ((u >> 16) & 1)) >> 16);
}
__device__ inline unsigned pack2(float lo, float hi) {
    return (unsigned)f2bf(lo) | ((unsigned)f2bf(hi) << 16);
}

// ---------------- CSR build (once per call) ----------------

__global__ __launch_bounds__(256) void hist_kernel(const int* __restrict__ dstv,
                                                   const int* __restrict__ typev,
                                                   int* __restrict__ hist) {
    int e = blockIdx.x * 256 + threadIdx.x;
    if (e < NE) atomicAdd(&hist[dstv[e] * 8 + typev[e]], 1);
}

__global__ __launch_bounds__(256) void scan1_kernel(const int* __restrict__ hist,
                                                    int* __restrict__ excl,
                                                    int* __restrict__ bsums) {
    __shared__ int tmp[256];
    int tid = threadIdx.x;
    int base = blockIdx.x * 2048 + tid * 8;
    int v[8]; int s = 0;
#pragma unroll
    for (int i = 0; i < 8; ++i) {
        v[i] = (base + i < MM) ? hist[base + i] : 0;
        s += v[i];
    }
    tmp[tid] = s;
    __syncthreads();
    for (int off = 1; off < 256; off <<= 1) {
        int t = (tid >= off) ? tmp[tid - off] : 0;
        __syncthreads();
        tmp[tid] += t;
        __syncthreads();
    }
    int run = tmp[tid] - s;
#pragma unroll
    for (int i = 0; i < 8; ++i) {
        if (base + i < MM) excl[base + i] = run;
        run += v[i];
    }
    if (tid == 255) bsums[blockIdx.x] = tmp[255];
}

__global__ __launch_bounds__(128) void scan2_kernel(int* __restrict__ bsums) {
    __shared__ int tmp[128];
    int tid = threadIdx.x;
    int orig = (tid < NSB) ? bsums[tid] : 0;
    tmp[tid] = orig;
    __syncthreads();
    for (int off = 1; off < 128; off <<= 1) {
        int t = (tid >= off) ? tmp[tid - off] : 0;
        __syncthreads();
        tmp[tid] += t;
        __syncthreads();
    }
    if (tid < NSB) bsums[tid] = tmp[tid] - orig;
}

__global__ __launch_bounds__(256) void add_off_kernel(const int* __restrict__ excl,
                                                      const int* __restrict__ bsums,
                                                      int* __restrict__ seg_start,
                                                      int* __restrict__ cursor) {
    int i = blockIdx.x * 256 + threadIdx.x;
    if (i < MM) {
        int v = excl[i] + bsums[i >> 11];
        seg_start[i] = v;
        cursor[i] = v;
    }
    if (i == 0) seg_start[MM] = NE;
}

__global__ __launch_bounds__(256) void sort_scatter_kernel(
    const int* __restrict__ srcv, const int* __restrict__ dstv,
    const int* __restrict__ typev, int* __restrict__ cursor,
    int* __restrict__ esrc, int* __restrict__ eid) {
    int e = blockIdx.x * 256 + threadIdx.x;
    if (e < NE) {
        int key = dstv[e] * 8 + typev[e];
        int pos = atomicAdd(&cursor[key], 1);
        esrc[pos] = srcv[e];
        eid[pos]  = e;
    }
}

__global__ __launch_bounds__(256) void invdeg_kernel(const int* __restrict__ seg_start,
                                                     float* __restrict__ invdeg) {
    int i = blockIdx.x * 256 + threadIdx.x;
    if (i < NN) {
        int d = seg_start[i * 8 + 8] - seg_start[i * 8];
        invdeg[i] = 1.0f / (float)max(d, 1);
    }
}

// ---------------- once-per-call precomputes ----------------

__global__ __launch_bounds__(256) void eagg_kernel(
    const int* __restrict__ seg_start, const int* __restrict__ eid,
    const float* __restrict__ ee, const float* __restrict__ invdeg,
    unsigned short* __restrict__ eaggbf) {
    int tid = threadIdx.x;
    int s = blockIdx.x * 8 + (tid >> 5);
    int j = tid & 31;
    int n = s >> 3, r = s & 7;
    int j0 = seg_start[s], j1 = seg_start[s + 1];
    float sum = 0.0f;
    for (int p = j0; p < j1; ++p)
        sum += ee[eid[p] * EED + j];
    eaggbf[(size_t)n * DD + r * EED + j] = f2bf(sum * invdeg[n]);
}

// Whe split-K over 8 d-chunks of 32, fp32 atomics (Whe pre-zeroed)
__global__ __launch_bounds__(256) void whe_kernel(const float* __restrict__ We,
                                                  const float* __restrict__ W,
                                                  float* __restrict__ Whe) {
    __shared__ float WeS[EED * 32];
    int b = blockIdx.x;
    int l = b >> 6;
    int r = (b >> 3) & 7;
    int dc = b & 7;
    int tid = threadIdx.x;
    {
        int j = tid >> 3, dl = (tid & 7) * 4;
        *(float4*)&WeS[j * 32 + dl] =
            *(const float4*)&We[(size_t)l * EED * DD + (size_t)j * DD + dc * 32 + dl];
    }
    __syncthreads();
    const float* Wr = W + ((size_t)l * 8 + r) * DD * DD + (size_t)dc * 32 * DD;
    float acc[EED];
#pragma unroll
    for (int j = 0; j < EED; ++j) acc[j] = 0.0f;
    for (int dl = 0; dl < 32; ++dl) {
        float w = Wr[(size_t)dl * DD + tid];
#pragma unroll
        for (int j = 0; j < EED; ++j) acc[j] += WeS[j * 32 + dl] * w;
    }
    float* outp = Whe + (size_t)l * DD * DD + r * EED * DD + tid;
#pragma unroll
    for (int j = 0; j < EED; ++j) unsafeAtomicAdd(&outp[j * DD], acc[j]);
}

// B pre-swizzle into MFMA fragment order (bf16).
// Phase order: p=0 -> Wself, p=1..8 -> W[r=p-1], p=9 -> Whe.
// Bsw[l][(((p*8+kb)*4+quad)*256+f)*8+j] = B_l[p][kb*32+quad*8+j][f]
__global__ __launch_bounds__(256) void bswz_kernel(const float* __restrict__ W,
                                                   const float* __restrict__ Wself,
                                                   const float* __restrict__ Whe,
                                                   unsigned short* __restrict__ Bsw) {
    int gid = blockIdx.x * 256 + threadIdx.x;
    int f = gid & 255;
    int t = gid >> 8;
    int quad = t & 3; t >>= 2;
    int kb = t & 7; t >>= 3;
    int p = t % 10, l = t / 10;
    const float* base = (p == 0) ? Wself + (size_t)l * DD * DD
                      : (p <= 8) ? W + ((size_t)l * 8 + (p - 1)) * DD * DD
                                 : Whe + (size_t)l * DD * DD;
    int k0 = kb * 32 + quad * 8;
    unsigned pk[4];
#pragma unroll
    for (int jj = 0; jj < 4; ++jj)
        pk[jj] = pack2(base[(size_t)(k0 + 2 * jj) * DD + f],
                       base[(size_t)(k0 + 2 * jj + 1) * DD + f]);
    uint4 v = make_uint4(pk[0], pk[1], pk[2], pk[3]);
    *(uint4*)&Bsw[(size_t)gid * 8] = v;
}

__global__ __launch_bounds__(256) void init_x_kernel(float* __restrict__ x,
                                                     unsigned short* __restrict__ xbf) {
    int i = blockIdx.x * 256 + threadIdx.x;
    ((float4*)x)[i] = make_float4(1.f, 1.f, 1.f, 1.f);
    ((uint2*)xbf)[i] = make_uint2(0x3f803f80u, 0x3f803f80u);
}

// ---------------- fused per-layer kernel: CSR gather + MFMA + LN ----------------
// Block = 32 dst rows x 256 cols, 4 waves. K = 2560 as 10 phases x 256:
//   p=0: A = x rows (staged in prologue)            B = Wself
//   p=1..8: A = relation (p-1) aggregate            B = W[r]
//   p=9: A = eagg rows                              B = Whe
// PIPELINE (per phase, no barrier between issue and consume):
//   issue all gather loads for next A -> 8 MFMA steps on current A (hides
//   L2/L3 latency) -> sum+ds_write next A -> barrier.
// B fragments register-prefetched 2 g-steps ahead from pre-swizzled L2 layout.
__global__ __launch_bounds__(256, 3) void fused_layer_kernel(
    const int* __restrict__ seg_start, const int* __restrict__ esrc,
    const unsigned short* __restrict__ xbf, const unsigned short* __restrict__ eaggbf,
    const unsigned short* __restrict__ Bswl, const float* __restrict__ xin,
    const float* __restrict__ gl, const float* __restrict__ bl,
    float* __restrict__ xout, unsigned short* __restrict__ xbfout) {
    __shared__ __align__(16) unsigned char smem[32768 + 1040 + ES_CAP * 4];
    float* Hs = (float*)smem;                       // epilogue overlay (32 x HSTR)
    int* boundsS = (int*)(smem + 32768);            // 257 seg bounds
    int* esrcS   = (int*)(smem + 32768 + 1040);     // staged edge srcs
    int tid = threadIdx.x;
    int wave = tid >> 6, lane = tid & 63;
    int row0 = blockIdx.x * 32;
    int m = lane & 15, quad = lane >> 4;
    int sr = tid >> 5, sc = tid & 31;
    int colg = lane >> 1, half = lane & 1, cofs = lane * 4;
    f4 acc[2][4] = {};

    // ---- prologue: bounds, x tile, edge list, B prefetch ----
    {
        int idx = row0 * 8 + tid;
        boundsS[tid] = (idx <= MM) ? seg_start[idx] : NE;   // pad rows -> empty
        if (tid == 0) {
            int idx2 = row0 * 8 + 256;
            boundsS[256] = (idx2 <= MM) ? seg_start[idx2] : NE;
        }
    }
    uint4 xa[4];
#pragma unroll
    for (int i = 0; i < 4; ++i) {
        int row = i * 8 + sr;
        xa[i] = *(const uint4*)&xbf[(size_t)(row0 + row) * DD + sc * 8];
    }
    __syncthreads();                                // bounds visible
    int blk0 = boundsS[0];
    int blkE = boundsS[256] - blk0;
    for (int j = tid; j < ES_CAP; j += 256)
        esrcS[j] = (j < blkE) ? esrc[blk0 + j] : 0; // always-valid node ids
#pragma unroll
    for (int i = 0; i < 4; ++i) {
        int row = i * 8 + sr;
        *(uint4*)&smem[row * 512 + ((sc ^ row) * 16)] = xa[i];
    }
    bf8 breg[2][4];
#pragma unroll
    for (int nt = 0; nt < 4; ++nt) {
        breg[0][nt] = *(const bf8*)&Bswl[((size_t)quad * 256 + wave * 64 + nt * 16 + m) * 8];
        breg[1][nt] = *(const bf8*)&Bswl[((size_t)(4 + quad) * 256 + wave * 64 + nt * 16 + m) * 8];
    }
    __syncthreads();                                // esrcS + buf0 visible

    for (int p = 0; p < 10; ++p) {
        unsigned char* bufp = smem + (p & 1) * 16384;
        unsigned char* bufn = smem + ((p + 1) & 1) * 16384;
        // ---- ISSUE next-A loads (latency hidden behind this phase's MFMA) ----
        int jj0[8];
        uint2 gv[8][4];
        uint4 ea[4];
        if (p < 8) {
#pragma unroll
            for (int i = 0; i < 8; ++i) {
                int nl = wave * 8 + i;
                jj0[i] = boundsS[nl * 8 + p] - blk0;
            }
#pragma unroll
            for (int i = 0; i < 8; ++i)
#pragma unroll
                for (int q = 0; q < 4; ++q) {
                    int jc = jj0[i] + q;
                    jc = (jc < ES_CAP) ? jc : (ES_CAP - 1);
                    int src = esrcS[jc];
                    gv[i][q] = *(const uint2*)&xbf[(size_t)src * DD + cofs];
                }
        } else if (p == 8) {
#pragma unroll
            for (int i = 0; i < 4; ++i) {
                int row = i * 8 + sr;
                ea[i] = *(const uint4*)&eaggbf[(size_t)(row0 + row) * DD + sc * 8];
            }
        }
        // ---- 8 MFMA steps on bufp; B register-prefetch 2 steps ahead ----
#pragma unroll
        for (int kb = 0; kb < 8; ++kb) {
            bf8 afr[2];
#pragma unroll
            for (int mt = 0; mt < 2; ++mt) {
                int rowl = mt * 16 + m;
                afr[mt] = *(bf8*)&bufp[rowl * 512 + (((kb * 4 + quad) ^ rowl) * 16)];
            }
#pragma unroll
            for (int mt = 0; mt < 2; ++mt)
#pragma unroll
                for (int nt = 0; nt < 4; ++nt)
                    acc[mt][nt] = __builtin_amdgcn_mfma_f32_16x16x32_bf16(
                        afr[mt], breg[kb & 1][nt], acc[mt][nt], 0, 0, 0);
            int gn = p * 8 + kb + 2;
            if (gn < 80) {
#pragma unroll
                for (int nt = 0; nt < 4; ++nt)
                    breg[kb & 1][nt] = *(const bf8*)&Bswl[((size_t)gn * 4 + quad) * 2048
                                                          + ((size_t)(wave * 64 + nt * 16 + m)) * 8];
            }
        }
        // ---- CONSUME: sum gathered rows, write next A buffer ----
        if (p < 8) {
#pragma unroll
            for (int i = 0; i < 8; ++i) {
                int nl = wave * 8 + i;
                int j0 = jj0[i];
                int j1 = boundsS[nl * 8 + p + 1] - blk0;
                int dgv = boundsS[nl * 8 + 8] - boundsS[nl * 8];
                float a0 = 0.f, a1 = 0.f, a2 = 0.f, a3 = 0.f;
#pragma unroll
                for (int q = 0; q < 4; ++q) {
                    unsigned vx = (j0 + q < j1) ? gv[i][q].x : 0u;
                    unsigned vy = (j0 + q < j1) ? gv[i][q].y : 0u;
                    a0 += lo2f(vx); a1 += hi2f(vx);
                    a2 += lo2f(vy); a3 += hi2f(vy);
                }
                for (int j = j0 + 4; j < j1; ++j) {   // rare tail (>4 edges/seg)
                    int src = (j < ES_CAP) ? esrcS[j] : esrc[blk0 + j];
                    uint2 v = *(const uint2*)&xbf[(size_t)src * DD + cofs];
                    a0 += lo2f(v.x); a1 += hi2f(v.x);
                    a2 += lo2f(v.y); a3 += hi2f(v.y);
                }
                float idg = 1.0f / (float)max(dgv, 1);
                uint2 o = make_uint2(pack2(a0 * idg, a1 * idg), pack2(a2 * idg, a3 * idg));
                *(uint2*)&bufn[nl * 512 + ((colg ^ nl) * 16) + half * 8] = o;
            }
        } else if (p == 8) {
#pragma unroll
            for (int i = 0; i < 4; ++i) {
                int row = i * 8 + sr;
                *(uint4*)&bufn[row * 512 + ((sc ^ row) * 16)] = ea[i];
            }
        }
        __syncthreads();
    }

    // ---- epilogue: residual prefetch; h tile through LDS; LN+ReLU+residual ----
    float4 xvr[8];
#pragma unroll
    for (int rr = 0; rr < 8; ++rr) {
        int row = wave * 8 + rr;
        xvr[rr] = *(const float4*)&xin[(size_t)(row0 + row) * DD + lane * 4];
    }
    float4 g  = *(const float4*)&gl[lane * 4];
    float4 bb = *(const float4*)&bl[lane * 4];
#pragma unroll
    for (int mt = 0; mt < 2; ++mt)
#pragma unroll
        for (int nt = 0; nt < 4; ++nt)
#pragma unroll
            for (int rg = 0; rg < 4; ++rg)
                Hs[(mt * 16 + quad * 4 + rg) * HSTR + wave * 64 + nt * 16 + m] = acc[mt][nt][rg];
    __syncthreads();
#pragma unroll
    for (int rr = 0; rr < 8; ++rr) {
        int row = wave * 8 + rr;
        float4 v = *(float4*)&Hs[row * HSTR + lane * 4];
        float s = v.x + v.y + v.z + v.w;
        float q = v.x * v.x + v.y * v.y + v.z * v.z + v.w * v.w;
#pragma unroll
        for (int off = 32; off; off >>= 1) {
            s += __shfl_xor(s, off);
            q += __shfl_xor(q, off);
        }
        float mu  = s * (1.0f / DD);
        float var = q * (1.0f / DD) - mu * mu;
        float rs  = rsqrtf(var + 1e-5f);
        size_t xi = (size_t)(row0 + row) * DD + lane * 4;
        float4 xv = xvr[rr];
        float4 o;
        o.x = fmaxf((v.x - mu) * rs * g.x + bb.x, 0.0f) + xv.x;
        o.y = fmaxf((v.y - mu) * rs * g.y + bb.y, 0.0f) + xv.y;
        o.z = fmaxf((v.z - mu) * rs * g.z + bb.z, 0.0f) + xv.z;
        o.w = fmaxf((v.w - mu) * rs * g.w + bb.w, 0.0f) + xv.w;
        *(float4*)&xout[xi] = o;
        *(uint2*)&xbfout[xi] = make_uint2(pack2(o.x, o.y), pack2(o.z, o.w));
    }
}

__global__ __launch_bounds__(256) void score_kernel(
    const int* __restrict__ batch, const float* __restrict__ x,
    const float* __restrict__ rel_emb, float* __restrict__ out) {
    int tid = threadIdx.x;
    int wave = tid >> 6, lane = tid & 63;
    int idx = blockIdx.x * 4 + wave;
    int s = batch[idx * 3 + 0], t = batch[idx * 3 + 1], r = batch[idx * 3 + 2];
    float4 sv = *(const float4*)&x[(size_t)s * DD + lane * 4];
    float4 tv = *(const float4*)&x[(size_t)t * DD + lane * 4];
    float4 rv = *(const float4*)&rel_emb[(size_t)r * DD + lane * 4];
    float sum = sv.x * rv.x * tv.x + sv.y * rv.y * tv.y +
                sv.z * rv.z * tv.z + sv.w * rv.w * tv.w;
#pragma unroll
    for (int off = 32; off; off >>= 1) sum += __shfl_xor(sum, off);
    if (lane == 0) out[idx] = sum;
}

extern "C" void kernel_launch(void* const* d_in, const int* in_sizes, int n_in,
                              void* d_out, int out_size, void* d_ws, size_t ws_size,
                              hipStream_t stream) {
    const int*   edge_index = (const int*)d_in[0];
    const int*   srcv   = edge_index;
    const int*   dstv   = edge_index + NE;
    const int*   typev  = (const int*)d_in[1];
    const float* ee     = (const float*)d_in[2];
    const int*   batch  = (const int*)d_in[3];
    const float* W      = (const float*)d_in[4];
    const float* Wself  = (const float*)d_in[5];
    const float* We     = (const float*)d_in[6];
    const float* gamma  = (const float*)d_in[7];
    const float* beta   = (const float*)d_in[8];
    const float* rel_emb= (const float*)d_in[9];
    float* out = (float*)d_out;

    // workspace layout
    float* xA     = (float*)d_ws;                          // NP*256 f32
    float* xB     = xA + (size_t)NP * DD;                  // NP*256 f32
    float* Whe    = xB + (size_t)NP * DD;                  // L*256*256 f32
    float* invdeg = Whe + (size_t)LL * DD * DD;            // NN f32
    unsigned short* xbfA   = (unsigned short*)(invdeg + NN);          // NP*256
    unsigned short* xbfB   = xbfA + (size_t)NP * DD;                  // NP*256
    unsigned short* eaggbf = xbfB + (size_t)NP * DD;                  // NP*256
    unsigned short* Bsw    = eaggbf + (size_t)NP * DD;                // L*2560*256
    int* hist      = (int*)(Bsw + (size_t)LL * 2560 * DD);            // M
    int* excl      = hist + MM;
    int* seg_start = excl + MM;                                       // M+1
    int* cursor    = seg_start + MM + 1;
    int* bsums     = cursor + MM;                                     // 256
    int* esrc      = bsums + 256;                                     // E
    int* eid       = esrc + NE;                                       // E

    // ---- CSR build ----
    hipMemsetAsync(hist, 0, MM * sizeof(int), stream);
    hist_kernel<<<(NE + 255) / 256, 256, 0, stream>>>(dstv, typev, hist);
    scan1_kernel<<<NSB, 256, 0, stream>>>(hist, excl, bsums);
    scan2_kernel<<<1, 128, 0, stream>>>(bsums);
    add_off_kernel<<<(MM + 255) / 256, 256, 0, stream>>>(excl, bsums, seg_start, cursor);
    invdeg_kernel<<<(NN + 255) / 256, 256, 0, stream>>>(seg_start, invdeg);
    sort_scatter_kernel<<<(NE + 255) / 256, 256, 0, stream>>>(srcv, dstv, typev, cursor, esrc, eid);

    // ---- precomputes ----
    eagg_kernel<<<MM / 8, 256, 0, stream>>>(seg_start, eid, ee, invdeg, eaggbf);
    hipMemsetAsync(Whe, 0, (size_t)LL * DD * DD * sizeof(float), stream);
    whe_kernel<<<LL * 64, 256, 0, stream>>>(We, W, Whe);
    bswz_kernel<<<LL * 10 * 8 * 4, 256, 0, stream>>>(W, Wself, Whe, Bsw);
    init_x_kernel<<<(NP * DD / 4) / 256, 256, 0, stream>>>(xA, xbfA);

    // ---- layers (x double-buffered), gather fused into the MFMA kernel ----
    float* xin = xA;  float* xout = xB;
    unsigned short* xbin = xbfA;  unsigned short* xbout = xbfB;
    for (int l = 0; l < LL; ++l) {
        fused_layer_kernel<<<NB2, 256, 0, stream>>>(seg_start, esrc, xbin, eaggbf,
            Bsw + (size_t)l * 2560 * DD, xin,
            gamma + (size_t)l * DD, beta + (size_t)l * DD, xout, xbout);
        float* t = xin; xin = xout; xout = t;
        unsigned short* tb = xbin; xbin = xbout; xbout = tb;
    }
    score_kernel<<<(BB * KK) / 4, 256, 0, stream>>>(batch, xin, rel_emb, out);
}

// Round 8
// 1064.028 us; speedup vs baseline: 1.1447x; 1.1447x over previous
//
#include <hip/hip_runtime.h>
#include <hip/hip_bf16.h>

#define NN 20000
#define NP 20032            // padded to 32*626
#define NE 320000
#define RR 8
#define DD 256
#define LL 6
#define EED 32
#define BB 64
#define KK 32
#define MM (NN * RR)        // 160000 segments, key = dst*8 + rel
#define NSB 79              // scan blocks: ceil(160000 / 2048)
#define NB2 626             // row blocks of 32
#define HSTR 260            // padded h-tile row stride (floats)
#define ES_CAP 1280         // per-block staged edge-list capacity (avg 512, max ~650)

typedef __bf16 bf8 __attribute__((ext_vector_type(8)));
typedef float f4 __attribute__((ext_vector_type(4)));

__device__ inline float lo2f(unsigned v) { return __uint_as_float(v << 16); }
__device__ inline float hi2f(unsigned v) { return __uint_as_float(v & 0xffff0000u); }
__device__ inline unsigned short f2bf(float f) {
    unsigned u = __float_as_uint(f);
    return (unsigned short)((u + 0x7fff + ((u >> 16) & 1)) >> 16);
}
__device__ inline unsigned pack2(float lo, float hi) {
    return (unsigned)f2bf(lo) | ((unsigned)f2bf(hi) << 16);
}

// ---------------- CSR build (once per call) ----------------

__global__ __launch_bounds__(256) void hist_kernel(const int* __restrict__ dstv,
                                                   const int* __restrict__ typev,
                                                   int* __restrict__ hist) {
    int e = blockIdx.x * 256 + threadIdx.x;
    if (e < NE) atomicAdd(&hist[dstv[e] * 8 + typev[e]], 1);
}

__global__ __launch_bounds__(256) void scan1_kernel(const int* __restrict__ hist,
                                                    int* __restrict__ excl,
                                                    int* __restrict__ bsums) {
    __shared__ int tmp[256];
    int tid = threadIdx.x;
    int base = blockIdx.x * 2048 + tid * 8;
    int v[8]; int s = 0;
#pragma unroll
    for (int i = 0; i < 8; ++i) {
        v[i] = (base + i < MM) ? hist[base + i] : 0;
        s += v[i];
    }
    tmp[tid] = s;
    __syncthreads();
    for (int off = 1; off < 256; off <<= 1) {
        int t = (tid >= off) ? tmp[tid - off] : 0;
        __syncthreads();
        tmp[tid] += t;
        __syncthreads();
    }
    int run = tmp[tid] - s;
#pragma unroll
    for (int i = 0; i < 8; ++i) {
        if (base + i < MM) excl[base + i] = run;
        run += v[i];
    }
    if (tid == 255) bsums[blockIdx.x] = tmp[255];
}

__global__ __launch_bounds__(128) void scan2_kernel(int* __restrict__ bsums) {
    __shared__ int tmp[128];
    int tid = threadIdx.x;
    int orig = (tid < NSB) ? bsums[tid] : 0;
    tmp[tid] = orig;
    __syncthreads();
    for (int off = 1; off < 128; off <<= 1) {
        int t = (tid >= off) ? tmp[tid - off] : 0;
        __syncthreads();
        tmp[tid] += t;
        __syncthreads();
    }
    if (tid < NSB) bsums[tid] = tmp[tid] - orig;
}

__global__ __launch_bounds__(256) void add_off_kernel(const int* __restrict__ excl,
                                                      const int* __restrict__ bsums,
                                                      int* __restrict__ seg_start,
                                                      int* __restrict__ cursor) {
    int i = blockIdx.x * 256 + threadIdx.x;
    if (i < MM) {
        int v = excl[i] + bsums[i >> 11];
        seg_start[i] = v;
        cursor[i] = v;
    }
    if (i == 0) seg_start[MM] = NE;
}

__global__ __launch_bounds__(256) void sort_scatter_kernel(
    const int* __restrict__ srcv, const int* __restrict__ dstv,
    const int* __restrict__ typev, int* __restrict__ cursor,
    int* __restrict__ esrc, int* __restrict__ eid) {
    int e = blockIdx.x * 256 + threadIdx.x;
    if (e < NE) {
        int key = dstv[e] * 8 + typev[e];
        int pos = atomicAdd(&cursor[key], 1);
        esrc[pos] = srcv[e];
        eid[pos]  = e;
    }
}

__global__ __launch_bounds__(256) void invdeg_kernel(const int* __restrict__ seg_start,
                                                     float* __restrict__ invdeg) {
    int i = blockIdx.x * 256 + threadIdx.x;
    if (i < NN) {
        int d = seg_start[i * 8 + 8] - seg_start[i * 8];
        invdeg[i] = 1.0f / (float)max(d, 1);
    }
}

// ---------------- once-per-call precomputes ----------------

__global__ __launch_bounds__(256) void eagg_kernel(
    const int* __restrict__ seg_start, const int* __restrict__ eid,
    const float* __restrict__ ee, const float* __restrict__ invdeg,
    unsigned short* __restrict__ eaggbf) {
    int tid = threadIdx.x;
    int s = blockIdx.x * 8 + (tid >> 5);
    int j = tid & 31;
    int n = s >> 3, r = s & 7;
    int j0 = seg_start[s], j1 = seg_start[s + 1];
    float sum = 0.0f;
    for (int p = j0; p < j1; ++p)
        sum += ee[eid[p] * EED + j];
    eaggbf[(size_t)n * DD + r * EED + j] = f2bf(sum * invdeg[n]);
}

// Whe split-K over 8 d-chunks of 32, fp32 atomics (Whe pre-zeroed)
__global__ __launch_bounds__(256) void whe_kernel(const float* __restrict__ We,
                                                  const float* __restrict__ W,
                                                  float* __restrict__ Whe) {
    __shared__ float WeS[EED * 32];
    int b = blockIdx.x;
    int l = b >> 6;
    int r = (b >> 3) & 7;
    int dc = b & 7;
    int tid = threadIdx.x;
    {
        int j = tid >> 3, dl = (tid & 7) * 4;
        *(float4*)&WeS[j * 32 + dl] =
            *(const float4*)&We[(size_t)l * EED * DD + (size_t)j * DD + dc * 32 + dl];
    }
    __syncthreads();
    const float* Wr = W + ((size_t)l * 8 + r) * DD * DD + (size_t)dc * 32 * DD;
    float acc[EED];
#pragma unroll
    for (int j = 0; j < EED; ++j) acc[j] = 0.0f;
    for (int dl = 0; dl < 32; ++dl) {
        float w = Wr[(size_t)dl * DD + tid];
#pragma unroll
        for (int j = 0; j < EED; ++j) acc[j] += WeS[j * 32 + dl] * w;
    }
    float* outp = Whe + (size_t)l * DD * DD + r * EED * DD + tid;
#pragma unroll
    for (int j = 0; j < EED; ++j) unsafeAtomicAdd(&outp[j * DD], acc[j]);
}

// B pre-swizzle into MFMA fragment order (bf16).
// Phase order: p=0 -> Wself, p=1..8 -> W[r=p-1], p=9 -> Whe.
// Bsw[l][(((p*8+kb)*4+quad)*256+f)*8+j] = B_l[p][kb*32+quad*8+j][f]
__global__ __launch_bounds__(256) void bswz_kernel(const float* __restrict__ W,
                                                   const float* __restrict__ Wself,
                                                   const float* __restrict__ Whe,
                                                   unsigned short* __restrict__ Bsw) {
    int gid = blockIdx.x * 256 + threadIdx.x;
    int f = gid & 255;
    int t = gid >> 8;
    int quad = t & 3; t >>= 2;
    int kb = t & 7; t >>= 3;
    int p = t % 10, l = t / 10;
    const float* base = (p == 0) ? Wself + (size_t)l * DD * DD
                      : (p <= 8) ? W + ((size_t)l * 8 + (p - 1)) * DD * DD
                                 : Whe + (size_t)l * DD * DD;
    int k0 = kb * 32 + quad * 8;
    unsigned pk[4];
#pragma unroll
    for (int jj = 0; jj < 4; ++jj)
        pk[jj] = pack2(base[(size_t)(k0 + 2 * jj) * DD + f],
                       base[(size_t)(k0 + 2 * jj + 1) * DD + f]);
    uint4 v = make_uint4(pk[0], pk[1], pk[2], pk[3]);
    *(uint4*)&Bsw[(size_t)gid * 8] = v;
}

__global__ __launch_bounds__(256) void init_x_kernel(float* __restrict__ x,
                                                     unsigned short* __restrict__ xbf) {
    int i = blockIdx.x * 256 + threadIdx.x;
    ((float4*)x)[i] = make_float4(1.f, 1.f, 1.f, 1.f);
    ((uint2*)xbf)[i] = make_uint2(0x3f803f80u, 0x3f803f80u);
}

// ---------------- fused per-layer kernel: CSR gather + MFMA + LN ----------------
// Block = 32 dst rows x 256 cols, EIGHT waves (512 thr):
//   wave w -> rows (w>>2)*16..+15, cols (w&3)*64..+63 (1x4 16x16 tiles)
// K = 2560 as 10 phases x 256 (p=0 self/x, p=1..8 relation r=p-1, p=9 eagg).
// Per phase: each wave gathers 4 rows of next A (issue close to use, R6
// structure), then 8 MFMA steps; ~20 waves/CU give inter-wave overlap.
__global__ __launch_bounds__(512, 4) void fused_layer_kernel(
    const int* __restrict__ seg_start, const int* __restrict__ esrc,
    const unsigned short* __restrict__ xbf, const unsigned short* __restrict__ eaggbf,
    const unsigned short* __restrict__ Bswl, const float* __restrict__ xin,
    const float* __restrict__ gl, const float* __restrict__ bl,
    float* __restrict__ xout, unsigned short* __restrict__ xbfout) {
    __shared__ __align__(16) unsigned char smem[32768 + 1040 + ES_CAP * 4];
    float* Hs = (float*)smem;                       // epilogue overlay (32 x HSTR)
    int* boundsS = (int*)(smem + 32768);            // 257 seg bounds
    int* esrcS   = (int*)(smem + 32768 + 1040);     // staged edge srcs
    int tid = threadIdx.x;
    int wave = tid >> 6, lane = tid & 63;
    int cwave = wave & 3, rwave = wave >> 2;
    int mrow0 = rwave * 16;
    int row0 = blockIdx.x * 32;
    int m = lane & 15, quad = lane >> 4;
    int sr = tid >> 5, sc = tid & 31;               // staging: 16 rows x 32 granules
    int colg = lane >> 1, half = lane & 1, cofs = lane * 4;
    f4 acc[4] = {};

    // ---- prologue: bounds, x tile, edge list, B prefetch ----
    if (tid < 257) {
        int idx = row0 * 8 + tid;
        boundsS[tid] = (idx <= MM) ? seg_start[idx] : NE;   // pad rows -> empty
    }
    uint4 xa[2];
#pragma unroll
    for (int i = 0; i < 2; ++i) {
        int row = i * 16 + sr;
        xa[i] = *(const uint4*)&xbf[(size_t)(row0 + row) * DD + sc * 8];
    }
    __syncthreads();                                // bounds visible
    int blk0 = boundsS[0];
    int blkE = boundsS[256] - blk0;
    for (int j = tid; j < ES_CAP; j += 512)
        esrcS[j] = (j < blkE) ? esrc[blk0 + j] : 0; // always-valid node ids
#pragma unroll
    for (int i = 0; i < 2; ++i) {
        int row = i * 16 + sr;
        *(uint4*)&smem[row * 512 + ((sc ^ row) * 16)] = xa[i];
    }
    bf8 breg[2][4];
#pragma unroll
    for (int nt = 0; nt < 4; ++nt) {
        breg[0][nt] = *(const bf8*)&Bswl[((size_t)quad * 256 + cwave * 64 + nt * 16 + m) * 8];
        breg[1][nt] = *(const bf8*)&Bswl[((size_t)(4 + quad) * 256 + cwave * 64 + nt * 16 + m) * 8];
    }
    __syncthreads();                                // esrcS + buf0 visible

    for (int p = 0; p < 10; ++p) {
        unsigned char* bufp = smem + (p & 1) * 16384;
        unsigned char* bufn = smem + ((p + 1) & 1) * 16384;
        // ---- produce next A: each wave gathers its 4 rows (issue near use) ----
        if (p < 8) {
            int jj0[4], jj1[4], dg[4];
#pragma unroll
            for (int i = 0; i < 4; ++i) {
                int nl = wave * 4 + i;
                jj0[i] = boundsS[nl * 8 + p] - blk0;
                jj1[i] = boundsS[nl * 8 + p + 1] - blk0;
                dg[i]  = boundsS[nl * 8 + 8] - boundsS[nl * 8];
            }
            int srcq[4][4];
#pragma unroll
            for (int i = 0; i < 4; ++i)
#pragma unroll
                for (int q = 0; q < 4; ++q) {
                    int jc = jj0[i] + q;
                    jc = (jc < ES_CAP) ? jc : (ES_CAP - 1);
                    srcq[i][q] = esrcS[jc];
                }
            uint2 gv[4][4];
#pragma unroll
            for (int i = 0; i < 4; ++i)
#pragma unroll
                for (int q = 0; q < 4; ++q)
                    gv[i][q] = *(const uint2*)&xbf[(size_t)srcq[i][q] * DD + cofs];
#pragma unroll
            for (int i = 0; i < 4; ++i) {
                int nl = wave * 4 + i;
                int j0 = jj0[i], j1 = jj1[i];
                float a0 = 0.f, a1 = 0.f, a2 = 0.f, a3 = 0.f;
#pragma unroll
                for (int q = 0; q < 4; ++q) {
                    unsigned vx = (j0 + q < j1) ? gv[i][q].x : 0u;
                    unsigned vy = (j0 + q < j1) ? gv[i][q].y : 0u;
                    a0 += lo2f(vx); a1 += hi2f(vx);
                    a2 += lo2f(vy); a3 += hi2f(vy);
                }
                for (int j = j0 + 4; j < j1; ++j) {   // rare tail (>4 edges/seg)
                    int src = (j < ES_CAP) ? esrcS[j] : esrc[blk0 + j];
                    uint2 v = *(const uint2*)&xbf[(size_t)src * DD + cofs];
                    a0 += lo2f(v.x); a1 += hi2f(v.x);
                    a2 += lo2f(v.y); a3 += hi2f(v.y);
                }
                float idg = 1.0f / (float)max(dg[i], 1);
                uint2 o = make_uint2(pack2(a0 * idg, a1 * idg), pack2(a2 * idg, a3 * idg));
                *(uint2*)&bufn[nl * 512 + ((colg ^ nl) * 16) + half * 8] = o;
            }
        } else if (p == 8) {
#pragma unroll
            for (int i = 0; i < 2; ++i) {
                int row = i * 16 + sr;
                uint4 v = *(const uint4*)&eaggbf[(size_t)(row0 + row) * DD + sc * 8];
                *(uint4*)&bufn[row * 512 + ((sc ^ row) * 16)] = v;
            }
        }
        // ---- 8 MFMA steps on bufp; B register-prefetch 2 steps ahead ----
#pragma unroll
        for (int kb = 0; kb < 8; ++kb) {
            int rowl = mrow0 + m;
            bf8 afr = *(bf8*)&bufp[rowl * 512 + (((kb * 4 + quad) ^ rowl) * 16)];
#pragma unroll
            for (int nt = 0; nt < 4; ++nt)
                acc[nt] = __builtin_amdgcn_mfma_f32_16x16x32_bf16(
                    afr, breg[kb & 1][nt], acc[nt], 0, 0, 0);
            int gn = p * 8 + kb + 2;
            if (gn < 80) {
#pragma unroll
                for (int nt = 0; nt < 4; ++nt)
                    breg[kb & 1][nt] = *(const bf8*)&Bswl[((size_t)gn * 4 + quad) * 2048
                                                          + ((size_t)(cwave * 64 + nt * 16 + m)) * 8];
            }
        }
        __syncthreads();
    }

    // ---- epilogue: residual prefetch; h tile through LDS; LN+ReLU+residual ----
    float4 xvr[4];
#pragma unroll
    for (int rr = 0; rr < 4; ++rr) {
        int row = wave * 4 + rr;
        xvr[rr] = *(const float4*)&xin[(size_t)(row0 + row) * DD + lane * 4];
    }
    float4 g  = *(const float4*)&gl[lane * 4];
    float4 bb = *(const float4*)&bl[lane * 4];
#pragma unroll
    for (int nt = 0; nt < 4; ++nt)
#pragma unroll
        for (int rg = 0; rg < 4; ++rg)
            Hs[(mrow0 + quad * 4 + rg) * HSTR + cwave * 64 + nt * 16 + m] = acc[nt][rg];
    __syncthreads();
#pragma unroll
    for (int rr = 0; rr < 4; ++rr) {
        int row = wave * 4 + rr;
        float4 v = *(float4*)&Hs[row * HSTR + lane * 4];
        float s = v.x + v.y + v.z + v.w;
        float q = v.x * v.x + v.y * v.y + v.z * v.z + v.w * v.w;
#pragma unroll
        for (int off = 32; off; off >>= 1) {
            s += __shfl_xor(s, off);
            q += __shfl_xor(q, off);
        }
        float mu  = s * (1.0f / DD);
        float var = q * (1.0f / DD) - mu * mu;
        float rs  = rsqrtf(var + 1e-5f);
        size_t xi = (size_t)(row0 + row) * DD + lane * 4;
        float4 xv = xvr[rr];
        float4 o;
        o.x = fmaxf((v.x - mu) * rs * g.x + bb.x, 0.0f) + xv.x;
        o.y = fmaxf((v.y - mu) * rs * g.y + bb.y, 0.0f) + xv.y;
        o.z = fmaxf((v.z - mu) * rs * g.z + bb.z, 0.0f) + xv.z;
        o.w = fmaxf((v.w - mu) * rs * g.w + bb.w, 0.0f) + xv.w;
        *(float4*)&xout[xi] = o;
        *(uint2*)&xbfout[xi] = make_uint2(pack2(o.x, o.y), pack2(o.z, o.w));
    }
}

__global__ __launch_bounds__(256) void score_kernel(
    const int* __restrict__ batch, const float* __restrict__ x,
    const float* __restrict__ rel_emb, float* __restrict__ out) {
    int tid = threadIdx.x;
    int wave = tid >> 6, lane = tid & 63;
    int idx = blockIdx.x * 4 + wave;
    int s = batch[idx * 3 + 0], t = batch[idx * 3 + 1], r = batch[idx * 3 + 2];
    float4 sv = *(const float4*)&x[(size_t)s * DD + lane * 4];
    float4 tv = *(const float4*)&x[(size_t)t * DD + lane * 4];
    float4 rv = *(const float4*)&rel_emb[(size_t)r * DD + lane * 4];
    float sum = sv.x * rv.x * tv.x + sv.y * rv.y * tv.y +
                sv.z * rv.z * tv.z + sv.w * rv.w * tv.w;
#pragma unroll
    for (int off = 32; off; off >>= 1) sum += __shfl_xor(sum, off);
    if (lane == 0) out[idx] = sum;
}

extern "C" void kernel_launch(void* const* d_in, const int* in_sizes, int n_in,
                              void* d_out, int out_size, void* d_ws, size_t ws_size,
                              hipStream_t stream) {
    const int*   edge_index = (const int*)d_in[0];
    const int*   srcv   = edge_index;
    const int*   dstv   = edge_index + NE;
    const int*   typev  = (const int*)d_in[1];
    const float* ee     = (const float*)d_in[2];
    const int*   batch  = (const int*)d_in[3];
    const float* W      = (const float*)d_in[4];
    const float* Wself  = (const float*)d_in[5];
    const float* We     = (const float*)d_in[6];
    const float* gamma  = (const float*)d_in[7];
    const float* beta   = (const float*)d_in[8];
    const float* rel_emb= (const float*)d_in[9];
    float* out = (float*)d_out;

    // workspace layout
    float* xA     = (float*)d_ws;                          // NP*256 f32
    float* xB     = xA + (size_t)NP * DD;                  // NP*256 f32
    float* Whe    = xB + (size_t)NP * DD;                  // L*256*256 f32
    float* invdeg = Whe + (size_t)LL * DD * DD;            // NN f32
    unsigned short* xbfA   = (unsigned short*)(invdeg + NN);          // NP*256
    unsigned short* xbfB   = xbfA + (size_t)NP * DD;                  // NP*256
    unsigned short* eaggbf = xbfB + (size_t)NP * DD;                  // NP*256
    unsigned short* Bsw    = eaggbf + (size_t)NP * DD;                // L*2560*256
    int* hist      = (int*)(Bsw + (size_t)LL * 2560 * DD);            // M
    int* excl      = hist + MM;
    int* seg_start = excl + MM;                                       // M+1
    int* cursor    = seg_start + MM + 1;
    int* bsums     = cursor + MM;                                     // 256
    int* esrc      = bsums + 256;                                     // E
    int* eid       = esrc + NE;                                       // E

    // ---- CSR build ----
    hipMemsetAsync(hist, 0, MM * sizeof(int), stream);
    hist_kernel<<<(NE + 255) / 256, 256, 0, stream>>>(dstv, typev, hist);
    scan1_kernel<<<NSB, 256, 0, stream>>>(hist, excl, bsums);
    scan2_kernel<<<1, 128, 0, stream>>>(bsums);
    add_off_kernel<<<(MM + 255) / 256, 256, 0, stream>>>(excl, bsums, seg_start, cursor);
    invdeg_kernel<<<(NN + 255) / 256, 256, 0, stream>>>(seg_start, invdeg);
    sort_scatter_kernel<<<(NE + 255) / 256, 256, 0, stream>>>(srcv, dstv, typev, cursor, esrc, eid);

    // ---- precomputes ----
    eagg_kernel<<<MM / 8, 256, 0, stream>>>(seg_start, eid, ee, invdeg, eaggbf);
    hipMemsetAsync(Whe, 0, (size_t)LL * DD * DD * sizeof(float), stream);
    whe_kernel<<<LL * 64, 256, 0, stream>>>(We, W, Whe);
    bswz_kernel<<<LL * 10 * 8 * 4, 256, 0, stream>>>(W, Wself, Whe, Bsw);
    init_x_kernel<<<(NP * DD / 4) / 256, 256, 0, stream>>>(xA, xbfA);

    // ---- layers (x double-buffered), gather fused into the MFMA kernel ----
    float* xin = xA;  float* xout = xB;
    unsigned short* xbin = xbfA;  unsigned short* xbout = xbfB;
    for (int l = 0; l < LL; ++l) {
        fused_layer_kernel<<<NB2, 512, 0, stream>>>(seg_start, esrc, xbin, eaggbf,
            Bsw + (size_t)l * 2560 * DD, xin,
            gamma + (size_t)l * DD, beta + (size_t)l * DD, xout, xbout);
        float* t = xin; xin = xout; xout = t;
        unsigned short* tb = xbin; xbin = xbout; xbout = tb;
    }
    score_kernel<<<(BB * KK) / 4, 256, 0, stream>>>(batch, xin, rel_emb, out);
}

// Round 9
// 1056.517 us; speedup vs baseline: 1.1529x; 1.0071x over previous
//
#include <hip/hip_runtime.h>
#include <hip/hip_bf16.h>

#define NN 20000
#define NP 20032            // padded to 32*626
#define NE 320000
#define RR 8
#define DD 256
#define LL 6
#define EED 32
#define BB 64
#define KK 32
#define MM (NN * RR)        // 160000 segments, key = dst*8 + rel
#define NSB 79              // scan blocks: ceil(160000 / 2048)
#define NB2 626             // row blocks of 32
#define HSTR 260            // padded h-tile row stride (floats)

typedef __bf16 bf8 __attribute__((ext_vector_type(8)));
typedef float f4 __attribute__((ext_vector_type(4)));
typedef const __attribute__((address_space(1))) unsigned int* as1_u32p;
typedef __attribute__((address_space(3))) unsigned int* as3_u32p;

__device__ inline float lo2f(unsigned v) { return __uint_as_float(v << 16); }
__device__ inline float hi2f(unsigned v) { return __uint_as_float(v & 0xffff0000u); }
__device__ inline unsigned short f2bf(float f) {
    unsigned u = __float_as_uint(f);
    return (unsigned short)((u + 0x7fff + ((u >> 16) & 1)) >> 16);
}
__device__ inline unsigned pack2(float lo, float hi) {
    return (unsigned)f2bf(lo) | ((unsigned)f2bf(hi) << 16);
}

// async 16KB tile DMA: linear global -> linear LDS (each call: 1KB per wave)
__device__ inline void dma_tile(const unsigned short* gtile, unsigned char* ldsbase,
                                int wave, int lane) {
#pragma unroll
    for (int c = 0; c < 4; ++c) {
        const void* g = (const unsigned char*)gtile + (wave * 4 + c) * 1024 + lane * 16;
        void* s = ldsbase + (wave * 4 + c) * 1024;     // + lane*16 by HW
        __builtin_amdgcn_global_load_lds((as1_u32p)g, (as3_u32p)s, 16, 0, 0);
    }
}

// ---------------- CSR build (once per call) ----------------

__global__ __launch_bounds__(256) void hist_kernel(const int* __restrict__ dstv,
                                                   const int* __restrict__ typev,
                                                   int* __restrict__ hist) {
    int e = blockIdx.x * 256 + threadIdx.x;
    if (e < NE) atomicAdd(&hist[dstv[e] * 8 + typev[e]], 1);
}

__global__ __launch_bounds__(256) void scan1_kernel(const int* __restrict__ hist,
                                                    int* __restrict__ excl,
                                                    int* __restrict__ bsums) {
    __shared__ int tmp[256];
    int tid = threadIdx.x;
    int base = blockIdx.x * 2048 + tid * 8;
    int v[8]; int s = 0;
#pragma unroll
    for (int i = 0; i < 8; ++i) {
        v[i] = (base + i < MM) ? hist[base + i] : 0;
        s += v[i];
    }
    tmp[tid] = s;
    __syncthreads();
    for (int off = 1; off < 256; off <<= 1) {
        int t = (tid >= off) ? tmp[tid - off] : 0;
        __syncthreads();
        tmp[tid] += t;
        __syncthreads();
    }
    int run = tmp[tid] - s;
#pragma unroll
    for (int i = 0; i < 8; ++i) {
        if (base + i < MM) excl[base + i] = run;
        run += v[i];
    }
    if (tid == 255) bsums[blockIdx.x] = tmp[255];
}

__global__ __launch_bounds__(128) void scan2_kernel(int* __restrict__ bsums) {
    __shared__ int tmp[128];
    int tid = threadIdx.x;
    int orig = (tid < NSB) ? bsums[tid] : 0;
    tmp[tid] = orig;
    __syncthreads();
    for (int off = 1; off < 128; off <<= 1) {
        int t = (tid >= off) ? tmp[tid - off] : 0;
        __syncthreads();
        tmp[tid] += t;
        __syncthreads();
    }
    if (tid < NSB) bsums[tid] = tmp[tid] - orig;
}

__global__ __launch_bounds__(256) void add_off_kernel(const int* __restrict__ excl,
                                                      const int* __restrict__ bsums,
                                                      int* __restrict__ seg_start,
                                                      int* __restrict__ cursor) {
    int i = blockIdx.x * 256 + threadIdx.x;
    if (i < MM) {
        int v = excl[i] + bsums[i >> 11];
        seg_start[i] = v;
        cursor[i] = v;
    }
    if (i == 0) seg_start[MM] = NE;
}

__global__ __launch_bounds__(256) void sort_scatter_kernel(
    const int* __restrict__ srcv, const int* __restrict__ dstv,
    const int* __restrict__ typev, int* __restrict__ cursor,
    int* __restrict__ esrc, int* __restrict__ eid) {
    int e = blockIdx.x * 256 + threadIdx.x;
    if (e < NE) {
        int key = dstv[e] * 8 + typev[e];
        int pos = atomicAdd(&cursor[key], 1);
        esrc[pos] = srcv[e];
        eid[pos]  = e;
    }
}

__global__ __launch_bounds__(256) void invdeg_kernel(const int* __restrict__ seg_start,
                                                     float* __restrict__ invdeg) {
    int i = blockIdx.x * 256 + threadIdx.x;
    if (i < NN) {
        int d = seg_start[i * 8 + 8] - seg_start[i * 8];
        invdeg[i] = 1.0f / (float)max(d, 1);
    }
}

// ---------------- once-per-call precomputes ----------------

__global__ __launch_bounds__(256) void eagg_kernel(
    const int* __restrict__ seg_start, const int* __restrict__ eid,
    const float* __restrict__ ee, const float* __restrict__ invdeg,
    unsigned short* __restrict__ eaggbf) {
    int tid = threadIdx.x;
    int s = blockIdx.x * 8 + (tid >> 5);
    int j = tid & 31;
    int n = s >> 3, r = s & 7;
    int j0 = seg_start[s], j1 = seg_start[s + 1];
    float sum = 0.0f;
    for (int p = j0; p < j1; ++p)
        sum += ee[eid[p] * EED + j];
    eaggbf[(size_t)n * DD + r * EED + j] = f2bf(sum * invdeg[n]);
}

// Whe split-K over 8 d-chunks of 32, fp32 atomics (Whe pre-zeroed)
__global__ __launch_bounds__(256) void whe_kernel(const float* __restrict__ We,
                                                  const float* __restrict__ W,
                                                  float* __restrict__ Whe) {
    __shared__ float WeS[EED * 32];
    int b = blockIdx.x;
    int l = b >> 6;
    int r = (b >> 3) & 7;
    int dc = b & 7;
    int tid = threadIdx.x;
    {
        int j = tid >> 3, dl = (tid & 7) * 4;
        *(float4*)&WeS[j * 32 + dl] =
            *(const float4*)&We[(size_t)l * EED * DD + (size_t)j * DD + dc * 32 + dl];
    }
    __syncthreads();
    const float* Wr = W + ((size_t)l * 8 + r) * DD * DD + (size_t)dc * 32 * DD;
    float acc[EED];
#pragma unroll
    for (int j = 0; j < EED; ++j) acc[j] = 0.0f;
    for (int dl = 0; dl < 32; ++dl) {
        float w = Wr[(size_t)dl * DD + tid];
#pragma unroll
        for (int j = 0; j < EED; ++j) acc[j] += WeS[j * 32 + dl] * w;
    }
    float* outp = Whe + (size_t)l * DD * DD + r * EED * DD + tid;
#pragma unroll
    for (int j = 0; j < EED; ++j) unsafeAtomicAdd(&outp[j * DD], acc[j]);
}

// B pre-swizzle into MFMA fragment order (bf16).
// Phase order: p=0..7 -> W[r=p], p=8 -> Wself, p=9 -> Whe.
// Bsw[l][(((p*8+kb)*4+quad)*256+f)*8+j] = B_l[p][kb*32+quad*8+j][f]
__global__ __launch_bounds__(256) void bswz_kernel(const float* __restrict__ W,
                                                   const float* __restrict__ Wself,
                                                   const float* __restrict__ Whe,
                                                   unsigned short* __restrict__ Bsw) {
    int gid = blockIdx.x * 256 + threadIdx.x;
    int f = gid & 255;
    int t = gid >> 8;
    int quad = t & 3; t >>= 2;
    int kb = t & 7; t >>= 3;
    int p = t % 10, l = t / 10;
    const float* base = (p < 8) ? W + ((size_t)l * 8 + p) * DD * DD
                      : (p == 8) ? Wself + (size_t)l * DD * DD
                                 : Whe + (size_t)l * DD * DD;
    int k0 = kb * 32 + quad * 8;
    unsigned pk[4];
#pragma unroll
    for (int jj = 0; jj < 4; ++jj)
        pk[jj] = pack2(base[(size_t)(k0 + 2 * jj) * DD + f],
                       base[(size_t)(k0 + 2 * jj + 1) * DD + f]);
    uint4 v = make_uint4(pk[0], pk[1], pk[2], pk[3]);
    *(uint4*)&Bsw[(size_t)gid * 8] = v;
}

__global__ __launch_bounds__(256) void init_x_kernel(float* __restrict__ x,
                                                     unsigned short* __restrict__ xbf) {
    int i = blockIdx.x * 256 + threadIdx.x;
    ((float4*)x)[i] = make_float4(1.f, 1.f, 1.f, 1.f);
    ((uint2*)xbf)[i] = make_uint2(0x3f803f80u, 0x3f803f80u);
}

// ---------------- per-layer pass 1: CSR segment-sum into SWIZZLED bf16 tiles ----
// one wave per segment (n,r); lane covers 4 features. Output layout matches the
// linear global_load_lds LDS image: tile (r, n>>5), row rl=n&31, granule g
// holds logical granule (g ^ rl)  => write logical colg at position (colg^rl).
__global__ __launch_bounds__(256) void agg_build_kernel(
    const int* __restrict__ seg_start, const int* __restrict__ esrc,
    const unsigned short* __restrict__ xbf, const float* __restrict__ invdeg,
    unsigned short* __restrict__ aggbf) {
    int tid = threadIdx.x;
    int wave = tid >> 6, lane = tid & 63;
    int s = blockIdx.x * 4 + wave;
    int n = s >> 3, r = s & 7;
    int j0 = seg_start[s], j1 = seg_start[s + 1];
    float a0 = 0.f, a1 = 0.f, a2 = 0.f, a3 = 0.f;
    for (int j = j0; j < j1; ++j) {
        int src = esrc[j];
        uint2 v = *(const uint2*)&xbf[(size_t)src * DD + lane * 4];
        a0 += lo2f(v.x); a1 += hi2f(v.x);
        a2 += lo2f(v.y); a3 += hi2f(v.y);
    }
    float idg = invdeg[n];
    uint2 o = make_uint2(pack2(a0 * idg, a1 * idg), pack2(a2 * idg, a3 * idg));
    int rl = n & 31, nb = n >> 5;
    int colg = lane >> 1, half = lane & 1;
    unsigned short* dst = aggbf + (((size_t)r * NB2 + nb) * 32 + rl) * DD;
    *(uint2*)&dst[(colg ^ rl) * 8 + half * 4] = o;
}

// ---------------- per-layer pass 2: MFMA GEMM + LN + ReLU + residual ----------
// block = 32 rows x 256 cols, 4 waves (wave w -> cols w*64, 2x4 16x16 tiles).
// K = 2560 as 10 phases: p=0..7 relation tiles via ASYNC global_load_lds DMA
// (pre-swizzled aggbf -> linear copy lands conflict-free), p=8 x rows, p=9
// eagg rows (register-staged). Ring of 2 LDS buffers; DMA(p+1) issued right
// after barrier(p), drained by barrier(p+1) -- overlapped with 8 MFMA steps +
// B register-prefetch (2 g-steps ahead from pre-swizzled L2-resident Bsw).
__global__ __launch_bounds__(256) void layer_mfma_kernel(
    const unsigned short* __restrict__ aggbf, const unsigned short* __restrict__ xbf,
    const unsigned short* __restrict__ eaggbf, const unsigned short* __restrict__ Bswl,
    const float* __restrict__ xin, const float* __restrict__ gl,
    const float* __restrict__ bl, float* __restrict__ xout,
    unsigned short* __restrict__ xbfout) {
    __shared__ __align__(16) unsigned char smem[33536];  // ring 2x16KB; Hs overlay 32x260 f32
    float* Hs = (float*)smem;
    int tid = threadIdx.x;
    int wave = tid >> 6, lane = tid & 63;
    int row0 = blockIdx.x * 32;
    int m = lane & 15, quad = lane >> 4;
    int sr = tid >> 5, sc = tid & 31;
    f4 acc[2][4] = {};
    uint4 xa[4], ea[4];

    // prologue: DMA(0) = relation-0 tile -> ring0; B prefetch g=0,1
    dma_tile(aggbf + (size_t)blockIdx.x * 8192, smem, wave, lane);
    bf8 breg[2][4];
#pragma unroll
    for (int nt = 0; nt < 4; ++nt) {
        breg[0][nt] = *(const bf8*)&Bswl[((size_t)quad) * 2048 + (wave * 64 + nt * 16 + m) * 8];
        breg[1][nt] = *(const bf8*)&Bswl[((size_t)(4 + quad)) * 2048 + (wave * 64 + nt * 16 + m) * 8];
    }

    for (int p = 0; p < 10; ++p) {
        unsigned char* bufp = smem + (p & 1) * 16384;
        __syncthreads();   // drains DMA(p) (vmcnt(0)) + prev-phase reads done
        if (p < 7) {
            dma_tile(aggbf + ((size_t)(p + 1) * NB2 + blockIdx.x) * 8192,
                     smem + ((p + 1) & 1) * 16384, wave, lane);
        } else if (p == 7) {          // stage x rows for phase 8
#pragma unroll
            for (int i = 0; i < 4; ++i) {
                int row = i * 8 + sr;
                xa[i] = *(const uint4*)&xbf[(size_t)(row0 + row) * DD + sc * 8];
            }
        } else if (p == 8) {          // stage eagg rows for phase 9
#pragma unroll
            for (int i = 0; i < 4; ++i) {
                int row = i * 8 + sr;
                ea[i] = *(const uint4*)&eaggbf[(size_t)(row0 + row) * DD + sc * 8];
            }
        }
        // 8 MFMA steps on bufp; B register-prefetch 2 steps ahead
#pragma unroll
        for (int kb = 0; kb < 8; ++kb) {
            bf8 afr[2];
#pragma unroll
            for (int mt = 0; mt < 2; ++mt) {
                int rowl = mt * 16 + m;
                afr[mt] = *(bf8*)&bufp[rowl * 512 + (((kb * 4 + quad) ^ rowl) * 16)];
            }
#pragma unroll
            for (int mt = 0; mt < 2; ++mt)
#pragma unroll
                for (int nt = 0; nt < 4; ++nt)
                    acc[mt][nt] = __builtin_amdgcn_mfma_f32_16x16x32_bf16(
                        afr[mt], breg[kb & 1][nt], acc[mt][nt], 0, 0, 0);
            int gn = p * 8 + kb + 2;
            if (gn < 80) {
#pragma unroll
                for (int nt = 0; nt < 4; ++nt)
                    breg[kb & 1][nt] = *(const bf8*)&Bswl[((size_t)gn * 4 + quad) * 2048
                                                          + ((size_t)(wave * 64 + nt * 16 + m)) * 8];
            }
        }
        if (p == 7) {                 // write x tile (swizzled) -> ring0 for phase 8
#pragma unroll
            for (int i = 0; i < 4; ++i) {
                int row = i * 8 + sr;
                *(uint4*)&smem[row * 512 + ((sc ^ row) * 16)] = xa[i];
            }
        } else if (p == 8) {          // write eagg tile (swizzled) -> ring1 for phase 9
#pragma unroll
            for (int i = 0; i < 4; ++i) {
                int row = i * 8 + sr;
                *(uint4*)&smem[16384 + row * 512 + ((sc ^ row) * 16)] = ea[i];
            }
        }
    }

    // ---- epilogue: residual prefetch; h tile through LDS; LN+ReLU+residual ----
    float4 xvr[8];
#pragma unroll
    for (int rr = 0; rr < 8; ++rr) {
        int row = wave * 8 + rr;
        xvr[rr] = *(const float4*)&xin[(size_t)(row0 + row) * DD + lane * 4];
    }
    float4 g  = *(const float4*)&gl[lane * 4];
    float4 bb = *(const float4*)&bl[lane * 4];
    __syncthreads();   // last-phase ring reads done before Hs overlay
#pragma unroll
    for (int mt = 0; mt < 2; ++mt)
#pragma unroll
        for (int nt = 0; nt < 4; ++nt)
#pragma unroll
            for (int rg = 0; rg < 4; ++rg)
                Hs[(mt * 16 + quad * 4 + rg) * HSTR + wave * 64 + nt * 16 + m] = acc[mt][nt][rg];
    __syncthreads();
#pragma unroll
    for (int rr = 0; rr < 8; ++rr) {
        int row = wave * 8 + rr;
        float4 v = *(float4*)&Hs[row * HSTR + lane * 4];
        float s = v.x + v.y + v.z + v.w;
        float q = v.x * v.x + v.y * v.y + v.z * v.z + v.w * v.w;
#pragma unroll
        for (int off = 32; off; off >>= 1) {
            s += __shfl_xor(s, off);
            q += __shfl_xor(q, off);
        }
        float mu  = s * (1.0f / DD);
        float var = q * (1.0f / DD) - mu * mu;
        float rs  = rsqrtf(var + 1e-5f);
        size_t xi = (size_t)(row0 + row) * DD + lane * 4;
        float4 xv = xvr[rr];
        float4 o;
        o.x = fmaxf((v.x - mu) * rs * g.x + bb.x, 0.0f) + xv.x;
        o.y = fmaxf((v.y - mu) * rs * g.y + bb.y, 0.0f) + xv.y;
        o.z = fmaxf((v.z - mu) * rs * g.z + bb.z, 0.0f) + xv.z;
        o.w = fmaxf((v.w - mu) * rs * g.w + bb.w, 0.0f) + xv.w;
        *(float4*)&xout[xi] = o;
        *(uint2*)&xbfout[xi] = make_uint2(pack2(o.x, o.y), pack2(o.z, o.w));
    }
}

__global__ __launch_bounds__(256) void score_kernel(
    const int* __restrict__ batch, const float* __restrict__ x,
    const float* __restrict__ rel_emb, float* __restrict__ out) {
    int tid = threadIdx.x;
    int wave = tid >> 6, lane = tid & 63;
    int idx = blockIdx.x * 4 + wave;
    int s = batch[idx * 3 + 0], t = batch[idx * 3 + 1], r = batch[idx * 3 + 2];
    float4 sv = *(const float4*)&x[(size_t)s * DD + lane * 4];
    float4 tv = *(const float4*)&x[(size_t)t * DD + lane * 4];
    float4 rv = *(const float4*)&rel_emb[(size_t)r * DD + lane * 4];
    float sum = sv.x * rv.x * tv.x + sv.y * rv.y * tv.y +
                sv.z * rv.z * tv.z + sv.w * rv.w * tv.w;
#pragma unroll
    for (int off = 32; off; off >>= 1) sum += __shfl_xor(sum, off);
    if (lane == 0) out[idx] = sum;
}

extern "C" void kernel_launch(void* const* d_in, const int* in_sizes, int n_in,
                              void* d_out, int out_size, void* d_ws, size_t ws_size,
                              hipStream_t stream) {
    const int*   edge_index = (const int*)d_in[0];
    const int*   srcv   = edge_index;
    const int*   dstv   = edge_index + NE;
    const int*   typev  = (const int*)d_in[1];
    const float* ee     = (const float*)d_in[2];
    const int*   batch  = (const int*)d_in[3];
    const float* W      = (const float*)d_in[4];
    const float* Wself  = (const float*)d_in[5];
    const float* We     = (const float*)d_in[6];
    const float* gamma  = (const float*)d_in[7];
    const float* beta   = (const float*)d_in[8];
    const float* rel_emb= (const float*)d_in[9];
    float* out = (float*)d_out;

    // workspace layout
    float* xA     = (float*)d_ws;                          // NP*256 f32
    float* xB     = xA + (size_t)NP * DD;                  // NP*256 f32
    float* Whe    = xB + (size_t)NP * DD;                  // L*256*256 f32
    float* invdeg = Whe + (size_t)LL * DD * DD;            // NN f32
    unsigned short* aggbf  = (unsigned short*)(invdeg + NN);          // 8*626*32*256 (swizzled tiles)
    unsigned short* xbfA   = aggbf + (size_t)RR * NB2 * 32 * DD;      // NP*256
    unsigned short* xbfB   = xbfA + (size_t)NP * DD;                  // NP*256
    unsigned short* eaggbf = xbfB + (size_t)NP * DD;                  // NP*256
    unsigned short* Bsw    = eaggbf + (size_t)NP * DD;                // L*2560*256
    int* hist      = (int*)(Bsw + (size_t)LL * 2560 * DD);            // M
    int* excl      = hist + MM;
    int* seg_start = excl + MM;                                       // M+1
    int* cursor    = seg_start + MM + 1;
    int* bsums     = cursor + MM;                                     // 256
    int* esrc      = bsums + 256;                                     // E
    int* eid       = esrc + NE;                                       // E

    // ---- CSR build ----
    hipMemsetAsync(hist, 0, MM * sizeof(int), stream);
    hist_kernel<<<(NE + 255) / 256, 256, 0, stream>>>(dstv, typev, hist);
    scan1_kernel<<<NSB, 256, 0, stream>>>(hist, excl, bsums);
    scan2_kernel<<<1, 128, 0, stream>>>(bsums);
    add_off_kernel<<<(MM + 255) / 256, 256, 0, stream>>>(excl, bsums, seg_start, cursor);
    invdeg_kernel<<<(NN + 255) / 256, 256, 0, stream>>>(seg_start, invdeg);
    sort_scatter_kernel<<<(NE + 255) / 256, 256, 0, stream>>>(srcv, dstv, typev, cursor, esrc, eid);

    // ---- precomputes ----
    eagg_kernel<<<MM / 8, 256, 0, stream>>>(seg_start, eid, ee, invdeg, eaggbf);
    hipMemsetAsync(Whe, 0, (size_t)LL * DD * DD * sizeof(float), stream);
    whe_kernel<<<LL * 64, 256, 0, stream>>>(We, W, Whe);
    bswz_kernel<<<LL * 10 * 8 * 4, 256, 0, stream>>>(W, Wself, Whe, Bsw);
    // zero pad tile rows of aggbf's last block (rows 20000..20031 never written)
    hipMemsetAsync(aggbf, 0, (size_t)RR * NB2 * 32 * DD * sizeof(short), stream);
    init_x_kernel<<<(NP * DD / 4) / 256, 256, 0, stream>>>(xA, xbfA);

    // ---- layers (x double-buffered): gather pass + async-DMA MFMA pass ----
    float* xin = xA;  float* xout = xB;
    unsigned short* xbin = xbfA;  unsigned short* xbout = xbfB;
    for (int l = 0; l < LL; ++l) {
        agg_build_kernel<<<MM / 4, 256, 0, stream>>>(seg_start, esrc, xbin, invdeg, aggbf);
        layer_mfma_kernel<<<NB2, 256, 0, stream>>>(aggbf, xbin, eaggbf,
            Bsw + (size_t)l * 2560 * DD, xin,
            gamma + (size_t)l * DD, beta + (size_t)l * DD, xout, xbout);
        float* t = xin; xin = xout; xout = t;
        unsigned short* tb = xbin; xbin = xbout; xbout = tb;
    }
    score_kernel<<<(BB * KK) / 4, 256, 0, stream>>>(batch, xin, rel_emb, out);
}

// Round 10
// 891.740 us; speedup vs baseline: 1.3659x; 1.1848x over previous
//
#include <hip/hip_runtime.h>
#include <hip/hip_bf16.h>

#define NN 20000
#define NP 20032            // padded to 32*626
#define NE 320000
#define RR 8
#define DD 256
#define LL 6
#define EED 32
#define BB 64
#define KK 32
#define MM (NN * RR)        // 160000 segments, key = dst*8 + rel
#define NSB 79              // scan blocks: ceil(160000 / 2048)
#define NB2 626             // row blocks of 32
#define HSTR 260            // padded h-tile row stride (floats)
#define ES_CAP 1280         // per-block staged edge-list capacity (avg 512, max ~650)

typedef __bf16 bf8 __attribute__((ext_vector_type(8)));
typedef float f4 __attribute__((ext_vector_type(4)));

__device__ inline float lo2f(unsigned v) { return __uint_as_float(v << 16); }
__device__ inline float hi2f(unsigned v) { return __uint_as_float(v & 0xffff0000u); }
__device__ inline unsigned short f2bf(float f) {
    unsigned u = __float_as_uint(f);
    return (unsigned short)((u + 0x7fff + ((u >> 16) & 1)) >> 16);
}
__device__ inline unsigned pack2(float lo, float hi) {
    return (unsigned)f2bf(lo) | ((unsigned)f2bf(hi) << 16);
}

// ---------------- CSR build (once per call) ----------------

__global__ __launch_bounds__(256) void hist_kernel(const int* __restrict__ dstv,
                                                   const int* __restrict__ typev,
                                                   int* __restrict__ hist) {
    int e = blockIdx.x * 256 + threadIdx.x;
    if (e < NE) atomicAdd(&hist[dstv[e] * 8 + typev[e]], 1);
}

__global__ __launch_bounds__(256) void scan1_kernel(const int* __restrict__ hist,
                                                    int* __restrict__ excl,
                                                    int* __restrict__ bsums) {
    __shared__ int tmp[256];
    int tid = threadIdx.x;
    int base = blockIdx.x * 2048 + tid * 8;
    int v[8]; int s = 0;
#pragma unroll
    for (int i = 0; i < 8; ++i) {
        v[i] = (base + i < MM) ? hist[base + i] : 0;
        s += v[i];
    }
    tmp[tid] = s;
    __syncthreads();
    for (int off = 1; off < 256; off <<= 1) {
        int t = (tid >= off) ? tmp[tid - off] : 0;
        __syncthreads();
        tmp[tid] += t;
        __syncthreads();
    }
    int run = tmp[tid] - s;
#pragma unroll
    for (int i = 0; i < 8; ++i) {
        if (base + i < MM) excl[base + i] = run;
        run += v[i];
    }
    if (tid == 255) bsums[blockIdx.x] = tmp[255];
}

__global__ __launch_bounds__(128) void scan2_kernel(int* __restrict__ bsums) {
    __shared__ int tmp[128];
    int tid = threadIdx.x;
    int orig = (tid < NSB) ? bsums[tid] : 0;
    tmp[tid] = orig;
    __syncthreads();
    for (int off = 1; off < 128; off <<= 1) {
        int t = (tid >= off) ? tmp[tid - off] : 0;
        __syncthreads();
        tmp[tid] += t;
        __syncthreads();
    }
    if (tid < NSB) bsums[tid] = tmp[tid] - orig;
}

__global__ __launch_bounds__(256) void add_off_kernel(const int* __restrict__ excl,
                                                      const int* __restrict__ bsums,
                                                      int* __restrict__ seg_start,
                                                      int* __restrict__ cursor) {
    int i = blockIdx.x * 256 + threadIdx.x;
    if (i < MM) {
        int v = excl[i] + bsums[i >> 11];
        seg_start[i] = v;
        cursor[i] = v;
    }
    if (i == 0) seg_start[MM] = NE;
}

__global__ __launch_bounds__(256) void sort_scatter_kernel(
    const int* __restrict__ srcv, const int* __restrict__ dstv,
    const int* __restrict__ typev, int* __restrict__ cursor,
    int* __restrict__ esrc, int* __restrict__ eid) {
    int e = blockIdx.x * 256 + threadIdx.x;
    if (e < NE) {
        int key = dstv[e] * 8 + typev[e];
        int pos = atomicAdd(&cursor[key], 1);
        esrc[pos] = srcv[e];
        eid[pos]  = e;
    }
}

__global__ __launch_bounds__(256) void invdeg_kernel(const int* __restrict__ seg_start,
                                                     float* __restrict__ invdeg) {
    int i = blockIdx.x * 256 + threadIdx.x;
    if (i < NN) {
        int d = seg_start[i * 8 + 8] - seg_start[i * 8];
        invdeg[i] = 1.0f / (float)max(d, 1);
    }
}

// ---------------- once-per-call precomputes ----------------

__global__ __launch_bounds__(256) void eagg_kernel(
    const int* __restrict__ seg_start, const int* __restrict__ eid,
    const float* __restrict__ ee, const float* __restrict__ invdeg,
    unsigned short* __restrict__ eaggbf) {
    int tid = threadIdx.x;
    int s = blockIdx.x * 8 + (tid >> 5);
    int j = tid & 31;
    int n = s >> 3, r = s & 7;
    int j0 = seg_start[s], j1 = seg_start[s + 1];
    float sum = 0.0f;
    for (int p = j0; p < j1; ++p)
        sum += ee[eid[p] * EED + j];
    eaggbf[(size_t)n * DD + r * EED + j] = f2bf(sum * invdeg[n]);
}

// Whe split-K over 8 d-chunks of 32, fp32 atomics (Whe pre-zeroed)
__global__ __launch_bounds__(256) void whe_kernel(const float* __restrict__ We,
                                                  const float* __restrict__ W,
                                                  float* __restrict__ Whe) {
    __shared__ float WeS[EED * 32];
    int b = blockIdx.x;
    int l = b >> 6;
    int r = (b >> 3) & 7;
    int dc = b & 7;
    int tid = threadIdx.x;
    {
        int j = tid >> 3, dl = (tid & 7) * 4;
        *(float4*)&WeS[j * 32 + dl] =
            *(const float4*)&We[(size_t)l * EED * DD + (size_t)j * DD + dc * 32 + dl];
    }
    __syncthreads();
    const float* Wr = W + ((size_t)l * 8 + r) * DD * DD + (size_t)dc * 32 * DD;
    float acc[EED];
#pragma unroll
    for (int j = 0; j < EED; ++j) acc[j] = 0.0f;
    for (int dl = 0; dl < 32; ++dl) {
        float w = Wr[(size_t)dl * DD + tid];
#pragma unroll
        for (int j = 0; j < EED; ++j) acc[j] += WeS[j * 32 + dl] * w;
    }
    float* outp = Whe + (size_t)l * DD * DD + r * EED * DD + tid;
#pragma unroll
    for (int j = 0; j < EED; ++j) unsafeAtomicAdd(&outp[j * DD], acc[j]);
}

// B pre-swizzle into MFMA fragment order (bf16).
// Phase order: p=0 -> Wself, p=1..8 -> W[r=p-1], p=9 -> Whe.
// Bsw[l][(((p*8+kb)*4+quad)*256+f)*8+j] = B_l[p][kb*32+quad*8+j][f]
__global__ __launch_bounds__(256) void bswz_kernel(const float* __restrict__ W,
                                                   const float* __restrict__ Wself,
                                                   const float* __restrict__ Whe,
                                                   unsigned short* __restrict__ Bsw) {
    int gid = blockIdx.x * 256 + threadIdx.x;
    int f = gid & 255;
    int t = gid >> 8;
    int quad = t & 3; t >>= 2;
    int kb = t & 7; t >>= 3;
    int p = t % 10, l = t / 10;
    const float* base = (p == 0) ? Wself + (size_t)l * DD * DD
                      : (p <= 8) ? W + ((size_t)l * 8 + (p - 1)) * DD * DD
                                 : Whe + (size_t)l * DD * DD;
    int k0 = kb * 32 + quad * 8;
    unsigned pk[4];
#pragma unroll
    for (int jj = 0; jj < 4; ++jj)
        pk[jj] = pack2(base[(size_t)(k0 + 2 * jj) * DD + f],
                       base[(size_t)(k0 + 2 * jj + 1) * DD + f]);
    uint4 v = make_uint4(pk[0], pk[1], pk[2], pk[3]);
    *(uint4*)&Bsw[(size_t)gid * 8] = v;
}

__global__ __launch_bounds__(256) void init_x_kernel(float* __restrict__ x,
                                                     unsigned short* __restrict__ xbf) {
    int i = blockIdx.x * 256 + threadIdx.x;
    ((float4*)x)[i] = make_float4(1.f, 1.f, 1.f, 1.f);
    ((uint2*)xbf)[i] = make_uint2(0x3f803f80u, 0x3f803f80u);
}

// ------- fused per-layer kernel: producer/consumer waves, gather + MFMA + LN -------
// Block = 32 dst rows x 256 cols, 8 waves (512 thr):
//   waves 0..3 (CONSUMERS, SIMDs 0-3): MFMA on buf[p], cols cwave*64..+63,
//     B fragments register-prefetched 2 g-steps ahead from pre-swizzled Bsw.
//   waves 4..7 (PRODUCERS, SIMDs 0-3): CSR-gather relation p into buf[p+1]
//     (rows cwave*8..+7); p==8 stages eagg tile. Gather latency overlaps the
//     consumers' MFMA on the same SIMD (separate pipes).
// K = 2560 as 10 phases x 256 (p=0 self/x, p=1..8 relation r=p-1, p=9 eagg/Whe).
__global__ __launch_bounds__(512, 2) void fused_layer_kernel(
    const int* __restrict__ seg_start, const int* __restrict__ esrc,
    const unsigned short* __restrict__ xbf, const unsigned short* __restrict__ eaggbf,
    const unsigned short* __restrict__ Bswl, const float* __restrict__ xin,
    const float* __restrict__ gl, const float* __restrict__ bl,
    float* __restrict__ xout, unsigned short* __restrict__ xbfout) {
    __shared__ __align__(16) unsigned char smem[32768 + 1040 + ES_CAP * 4];
    float* Hs = (float*)smem;                       // epilogue overlay (32 x HSTR)
    int* boundsS = (int*)(smem + 32768);            // 257 seg bounds
    int* esrcS   = (int*)(smem + 32768 + 1040);     // staged edge srcs
    int tid = threadIdx.x;
    int wave = tid >> 6, lane = tid & 63;
    bool consumer = wave < 4;
    int cwave = wave & 3;                           // consumer col group / producer row group
    int row0 = blockIdx.x * 32;
    int m = lane & 15, quad = lane >> 4;
    int colg = lane >> 1, half = lane & 1, cofs = lane * 4;
    f4 acc[2][4] = {};

    // ---- prologue: bounds, x tile, edge list, B prefetch ----
    if (tid < 257) {
        int idx = row0 * 8 + tid;
        boundsS[tid] = (idx <= MM) ? seg_start[idx] : NE;   // pad rows -> empty
    }
    uint4 xs[2];
#pragma unroll
    for (int c = 0; c < 2; ++c) {
        int i = tid + c * 512;
        int row = i >> 5, sc = i & 31;
        xs[c] = *(const uint4*)&xbf[(size_t)(row0 + row) * DD + sc * 8];
    }
    __syncthreads();                                // bounds visible
    int blk0 = boundsS[0];
    int blkE = boundsS[256] - blk0;
    for (int j = tid; j < ES_CAP; j += 512)
        esrcS[j] = (j < blkE) ? esrc[blk0 + j] : 0; // always-valid node ids
#pragma unroll
    for (int c = 0; c < 2; ++c) {
        int i = tid + c * 512;
        int row = i >> 5, sc = i & 31;
        *(uint4*)&smem[row * 512 + ((sc ^ row) * 16)] = xs[c];
    }
    bf8 breg[2][4];
    if (consumer) {
#pragma unroll
        for (int nt = 0; nt < 4; ++nt) {
            breg[0][nt] = *(const bf8*)&Bswl[((size_t)quad * 256 + cwave * 64 + nt * 16 + m) * 8];
            breg[1][nt] = *(const bf8*)&Bswl[((size_t)(4 + quad) * 256 + cwave * 64 + nt * 16 + m) * 8];
        }
    }
    __syncthreads();                                // esrcS + buf0 visible

    for (int p = 0; p < 10; ++p) {
        unsigned char* bufp = smem + (p & 1) * 16384;
        unsigned char* bufn = smem + ((p + 1) & 1) * 16384;
        if (consumer) {
            // ---- 8 MFMA steps on bufp; B register-prefetch 2 steps ahead ----
#pragma unroll
            for (int kb = 0; kb < 8; ++kb) {
                bf8 afr[2];
#pragma unroll
                for (int mt = 0; mt < 2; ++mt) {
                    int rowl = mt * 16 + m;
                    afr[mt] = *(bf8*)&bufp[rowl * 512 + (((kb * 4 + quad) ^ rowl) * 16)];
                }
#pragma unroll
                for (int mt = 0; mt < 2; ++mt)
#pragma unroll
                    for (int nt = 0; nt < 4; ++nt)
                        acc[mt][nt] = __builtin_amdgcn_mfma_f32_16x16x32_bf16(
                            afr[mt], breg[kb & 1][nt], acc[mt][nt], 0, 0, 0);
                int gn = p * 8 + kb + 2;
                if (gn < 80) {
#pragma unroll
                    for (int nt = 0; nt < 4; ++nt)
                        breg[kb & 1][nt] = *(const bf8*)&Bswl[((size_t)gn * 4 + quad) * 2048
                                                              + ((size_t)(cwave * 64 + nt * 16 + m)) * 8];
                }
            }
        } else if (p < 8) {
            // ---- producer: gather relation r=p for rows cwave*8..+7 into bufn ----
#pragma unroll
            for (int grp = 0; grp < 2; ++grp) {
                int jj0[4], jj1[4], dg[4];
#pragma unroll
                for (int i = 0; i < 4; ++i) {
                    int nl = cwave * 8 + grp * 4 + i;
                    jj0[i] = boundsS[nl * 8 + p] - blk0;
                    jj1[i] = boundsS[nl * 8 + p + 1] - blk0;
                    dg[i]  = boundsS[nl * 8 + 8] - boundsS[nl * 8];
                }
                int srcq[4][4];
#pragma unroll
                for (int i = 0; i < 4; ++i)
#pragma unroll
                    for (int q = 0; q < 4; ++q) {
                        int jc = jj0[i] + q;
                        jc = (jc < ES_CAP) ? jc : (ES_CAP - 1);
                        srcq[i][q] = esrcS[jc];
                    }
                uint2 gv[4][4];
#pragma unroll
                for (int i = 0; i < 4; ++i)
#pragma unroll
                    for (int q = 0; q < 4; ++q)
                        gv[i][q] = *(const uint2*)&xbf[(size_t)srcq[i][q] * DD + cofs];
#pragma unroll
                for (int i = 0; i < 4; ++i) {
                    int nl = cwave * 8 + grp * 4 + i;
                    int j0 = jj0[i], j1 = jj1[i];
                    float a0 = 0.f, a1 = 0.f, a2 = 0.f, a3 = 0.f;
#pragma unroll
                    for (int q = 0; q < 4; ++q) {
                        unsigned vx = (j0 + q < j1) ? gv[i][q].x : 0u;
                        unsigned vy = (j0 + q < j1) ? gv[i][q].y : 0u;
                        a0 += lo2f(vx); a1 += hi2f(vx);
                        a2 += lo2f(vy); a3 += hi2f(vy);
                    }
                    for (int j = j0 + 4; j < j1; ++j) {   // rare tail (>4 edges/seg)
                        int src = (j < ES_CAP) ? esrcS[j] : esrc[blk0 + j];
                        uint2 v = *(const uint2*)&xbf[(size_t)src * DD + cofs];
                        a0 += lo2f(v.x); a1 += hi2f(v.x);
                        a2 += lo2f(v.y); a3 += hi2f(v.y);
                    }
                    float idg = 1.0f / (float)max(dg[i], 1);
                    uint2 o = make_uint2(pack2(a0 * idg, a1 * idg), pack2(a2 * idg, a3 * idg));
                    *(uint2*)&bufn[nl * 512 + ((colg ^ nl) * 16) + half * 8] = o;
                }
            }
        } else if (p == 8) {
            // ---- producer: stage eagg rows cwave*8..+7 (2 rows / iter) ----
#pragma unroll
            for (int it = 0; it < 4; ++it) {
                int row = cwave * 8 + it * 2 + (lane >> 5);
                int sc = lane & 31;
                uint4 v = *(const uint4*)&eaggbf[(size_t)(row0 + row) * DD + sc * 8];
                *(uint4*)&bufn[row * 512 + ((sc ^ row) * 16)] = v;
            }
        }
        __syncthreads();
    }

    // ---- epilogue: residual prefetch; h tile through LDS; LN+ReLU+residual ----
    float4 xvr[4];
#pragma unroll
    for (int rr = 0; rr < 4; ++rr) {
        int row = wave * 4 + rr;
        xvr[rr] = *(const float4*)&xin[(size_t)(row0 + row) * DD + lane * 4];
    }
    float4 g  = *(const float4*)&gl[lane * 4];
    float4 bb = *(const float4*)&bl[lane * 4];
    if (consumer) {
#pragma unroll
        for (int mt = 0; mt < 2; ++mt)
#pragma unroll
            for (int nt = 0; nt < 4; ++nt)
#pragma unroll
                for (int rg = 0; rg < 4; ++rg)
                    Hs[(mt * 16 + quad * 4 + rg) * HSTR + cwave * 64 + nt * 16 + m] = acc[mt][nt][rg];
    }
    __syncthreads();
#pragma unroll
    for (int rr = 0; rr < 4; ++rr) {
        int row = wave * 4 + rr;
        float4 v = *(float4*)&Hs[row * HSTR + lane * 4];
        float s = v.x + v.y + v.z + v.w;
        float q = v.x * v.x + v.y * v.y + v.z * v.z + v.w * v.w;
#pragma unroll
        for (int off = 32; off; off >>= 1) {
            s += __shfl_xor(s, off);
            q += __shfl_xor(q, off);
        }
        float mu  = s * (1.0f / DD);
        float var = q * (1.0f / DD) - mu * mu;
        float rs  = rsqrtf(var + 1e-5f);
        size_t xi = (size_t)(row0 + row) * DD + lane * 4;
        float4 xv = xvr[rr];
        float4 o;
        o.x = fmaxf((v.x - mu) * rs * g.x + bb.x, 0.0f) + xv.x;
        o.y = fmaxf((v.y - mu) * rs * g.y + bb.y, 0.0f) + xv.y;
        o.z = fmaxf((v.z - mu) * rs * g.z + bb.z, 0.0f) + xv.z;
        o.w = fmaxf((v.w - mu) * rs * g.w + bb.w, 0.0f) + xv.w;
        *(float4*)&xout[xi] = o;
        *(uint2*)&xbfout[xi] = make_uint2(pack2(o.x, o.y), pack2(o.z, o.w));
    }
}

__global__ __launch_bounds__(256) void score_kernel(
    const int* __restrict__ batch, const float* __restrict__ x,
    const float* __restrict__ rel_emb, float* __restrict__ out) {
    int tid = threadIdx.x;
    int wave = tid >> 6, lane = tid & 63;
    int idx = blockIdx.x * 4 + wave;
    int s = batch[idx * 3 + 0], t = batch[idx * 3 + 1], r = batch[idx * 3 + 2];
    float4 sv = *(const float4*)&x[(size_t)s * DD + lane * 4];
    float4 tv = *(const float4*)&x[(size_t)t * DD + lane * 4];
    float4 rv = *(const float4*)&rel_emb[(size_t)r * DD + lane * 4];
    float sum = sv.x * rv.x * tv.x + sv.y * rv.y * tv.y +
                sv.z * rv.z * tv.z + sv.w * rv.w * tv.w;
#pragma unroll
    for (int off = 32; off; off >>= 1) sum += __shfl_xor(sum, off);
    if (lane == 0) out[idx] = sum;
}

extern "C" void kernel_launch(void* const* d_in, const int* in_sizes, int n_in,
                              void* d_out, int out_size, void* d_ws, size_t ws_size,
                              hipStream_t stream) {
    const int*   edge_index = (const int*)d_in[0];
    const int*   srcv   = edge_index;
    const int*   dstv   = edge_index + NE;
    const int*   typev  = (const int*)d_in[1];
    const float* ee     = (const float*)d_in[2];
    const int*   batch  = (const int*)d_in[3];
    const float* W      = (const float*)d_in[4];
    const float* Wself  = (const float*)d_in[5];
    const float* We     = (const float*)d_in[6];
    const float* gamma  = (const float*)d_in[7];
    const float* beta   = (const float*)d_in[8];
    const float* rel_emb= (const float*)d_in[9];
    float* out = (float*)d_out;

    // workspace layout
    float* xA     = (float*)d_ws;                          // NP*256 f32
    float* xB     = xA + (size_t)NP * DD;                  // NP*256 f32
    float* Whe    = xB + (size_t)NP * DD;                  // L*256*256 f32
    float* invdeg = Whe + (size_t)LL * DD * DD;            // NN f32
    unsigned short* xbfA   = (unsigned short*)(invdeg + NN);          // NP*256
    unsigned short* xbfB   = xbfA + (size_t)NP * DD;                  // NP*256
    unsigned short* eaggbf = xbfB + (size_t)NP * DD;                  // NP*256
    unsigned short* Bsw    = eaggbf + (size_t)NP * DD;                // L*2560*256
    int* hist      = (int*)(Bsw + (size_t)LL * 2560 * DD);            // M
    int* excl      = hist + MM;
    int* seg_start = excl + MM;                                       // M+1
    int* cursor    = seg_start + MM + 1;
    int* bsums     = cursor + MM;                                     // 256
    int* esrc      = bsums + 256;                                     // E
    int* eid       = esrc + NE;                                       // E

    // ---- CSR build ----
    hipMemsetAsync(hist, 0, MM * sizeof(int), stream);
    hist_kernel<<<(NE + 255) / 256, 256, 0, stream>>>(dstv, typev, hist);
    scan1_kernel<<<NSB, 256, 0, stream>>>(hist, excl, bsums);
    scan2_kernel<<<1, 128, 0, stream>>>(bsums);
    add_off_kernel<<<(MM + 255) / 256, 256, 0, stream>>>(excl, bsums, seg_start, cursor);
    invdeg_kernel<<<(NN + 255) / 256, 256, 0, stream>>>(seg_start, invdeg);
    sort_scatter_kernel<<<(NE + 255) / 256, 256, 0, stream>>>(srcv, dstv, typev, cursor, esrc, eid);

    // ---- precomputes ----
    eagg_kernel<<<MM / 8, 256, 0, stream>>>(seg_start, eid, ee, invdeg, eaggbf);
    hipMemsetAsync(Whe, 0, (size_t)LL * DD * DD * sizeof(float), stream);
    whe_kernel<<<LL * 64, 256, 0, stream>>>(We, W, Whe);
    bswz_kernel<<<LL * 10 * 8 * 4, 256, 0, stream>>>(W, Wself, Whe, Bsw);
    init_x_kernel<<<(NP * DD / 4) / 256, 256, 0, stream>>>(xA, xbfA);

    // ---- layers (x double-buffered), producer/consumer fused kernel ----
    float* xin = xA;  float* xout = xB;
    unsigned short* xbin = xbfA;  unsigned short* xbout = xbfB;
    for (int l = 0; l < LL; ++l) {
        fused_layer_kernel<<<NB2, 512, 0, stream>>>(seg_start, esrc, xbin, eaggbf,
            Bsw + (size_t)l * 2560 * DD, xin,
            gamma + (size_t)l * DD, beta + (size_t)l * DD, xout, xbout);
        float* t = xin; xin = xout; xout = t;
        unsigned short* tb = xbin; xbin = xbout; xbout = tb;
    }
    score_kernel<<<(BB * KK) / 4, 256, 0, stream>>>(batch, xin, rel_emb, out);
}